// Round 1
// baseline (449.550 us; speedup 1.0000x reference)
//
#include <hip/hip_runtime.h>

#define F_IN  256
#define F_OUT 32

// ---------- zero cnt, detect edge-index dtype ----------
// int64 little-endian with values < 2^31 => every odd 32-bit word is zero.
__global__ __launch_bounds__(256) void k_zero(int* __restrict__ cnt,
                                              const int* __restrict__ ei,
                                              int* __restrict__ flag, int N) {
    int i = blockIdx.x * 256 + threadIdx.x;
    if (i < N) cnt[i] = 0;
    if (i == 0) {
        int o = 0;
        for (int k = 1; k < 64; k += 2) o |= ei[k];
        *flag = (o == 0) ? 1 : 0;
    }
}

__device__ __forceinline__ int load_idx(const int* __restrict__ ei, int i, int mode64) {
    return mode64 ? ei[2 * i] : ei[i];
}

// ---------- degree count (in-degree over dst): 4 edges/thread ----------
__global__ __launch_bounds__(256) void k_count(const int* __restrict__ ei,
                                               int* __restrict__ cnt,
                                               const int* __restrict__ flag,
                                               int E, int N) {
    int m64 = *flag;
    int t = blockIdx.x * 256 + threadIdx.x;
    int e0 = t * 4;
    if (e0 >= E) return;
    int d[4];
    if (e0 + 3 < E) {
        if (m64) {
            const int4* base = (const int4*)(ei + 2 * (size_t)E);
            int4 a = base[2 * t];
            int4 c = base[2 * t + 1];
            d[0] = a.x; d[1] = a.z; d[2] = c.x; d[3] = c.z;
        } else {
            int4 a = *(const int4*)(ei + (size_t)E + e0);
            d[0] = a.x; d[1] = a.y; d[2] = a.z; d[3] = a.w;
        }
        #pragma unroll
        for (int j = 0; j < 4; ++j)
            if ((unsigned)d[j] < (unsigned)N) atomicAdd(&cnt[d[j]], 1);
    } else {
        for (int e = e0; e < E; ++e) {
            int dd = load_idx(ei, E + e, m64);
            if ((unsigned)dd < (unsigned)N) atomicAdd(&cnt[dd], 1);
        }
    }
}

// ---------- scan stage 1: per-1024-chunk exclusive scan + block sums ----------
__global__ __launch_bounds__(256) void k_scan1(const int* __restrict__ cnt,
                                               int* __restrict__ off,
                                               int* __restrict__ bsum, int N) {
    __shared__ int sd[256];
    const int tid = threadIdx.x;
    const int i0 = blockIdx.x * 1024 + tid * 4;
    int4 v = make_int4(0, 0, 0, 0);
    if (i0 + 3 < N) v = *(const int4*)(cnt + i0);
    else {
        if (i0     < N) v.x = cnt[i0];
        if (i0 + 1 < N) v.y = cnt[i0 + 1];
        if (i0 + 2 < N) v.z = cnt[i0 + 2];
    }
    int s = v.x + v.y + v.z + v.w;
    int val = s;
    sd[tid] = val; __syncthreads();
    #pragma unroll
    for (int d2 = 1; d2 < 256; d2 <<= 1) {
        int t = (tid >= d2) ? sd[tid - d2] : 0;
        __syncthreads();
        val += t; sd[tid] = val; __syncthreads();
    }
    int excl = val - s;
    int4 o;
    o.x = excl;
    o.y = excl + v.x;
    o.z = excl + v.x + v.y;
    o.w = excl + v.x + v.y + v.z;
    if (i0 + 3 < N) *(int4*)(off + i0) = o;
    else {
        if (i0     < N) off[i0]     = o.x;
        if (i0 + 1 < N) off[i0 + 1] = o.y;
        if (i0 + 2 < N) off[i0 + 2] = o.z;
    }
    if (tid == 255) bsum[blockIdx.x] = val;
}

// ---------- scan stage 2: single block exclusive-scans bsum in place ----------
__global__ __launch_bounds__(256) void k_scan2(int* __restrict__ bsum, int nb) {
    __shared__ int sd[256];
    const int tid = threadIdx.x;
    const int base = tid * 4;
    int v[4]; int s = 0;
    #pragma unroll
    for (int j = 0; j < 4; ++j) {
        v[j] = (base + j < nb) ? bsum[base + j] : 0;
        s += v[j];
    }
    int val = s;
    sd[tid] = val; __syncthreads();
    #pragma unroll
    for (int d2 = 1; d2 < 256; d2 <<= 1) {
        int t = (tid >= d2) ? sd[tid - d2] : 0;
        __syncthreads();
        val += t; sd[tid] = val; __syncthreads();
    }
    int run = val - s;
    #pragma unroll
    for (int j = 0; j < 4; ++j) {
        if (base + j < nb) bsum[base + j] = run;
        run += v[j];
    }
}

// ---------- scan stage 3: add block offsets ----------
__global__ __launch_bounds__(256) void k_scan3(int* __restrict__ off,
                                               const int* __restrict__ bsum, int N) {
    int i = blockIdx.x * 256 + threadIdx.x;
    if (i < N) off[i] += bsum[i >> 10];
}

// ---------- register-tiled GEMM: hs[n][f] = (x@W)[n][f] * rsqrt(deg[n]+1) ----------
// block: 256 threads -> 128 rows x 32 cols; thread: 4 rows x 4 cols
#define KC 64
#define LDP 68
__global__ __launch_bounds__(256) void k_gemm(const float* __restrict__ x,
                                              const float* __restrict__ W,
                                              const int* __restrict__ cnt,
                                              float* __restrict__ hs, int N) {
    __shared__ __align__(16) float sx[128 * LDP];
    __shared__ __align__(16) float sWt[F_OUT * LDP];
    const int tid = threadIdx.x;
    const int fbase = tid & 7;
    const int rbase = tid >> 3;
    const int row0 = blockIdx.x * 128;

    float acc[4][4];
    #pragma unroll
    for (int j = 0; j < 4; ++j)
        #pragma unroll
        for (int m = 0; m < 4; ++m) acc[j][m] = 0.f;

    for (int c = 0; c < F_IN / KC; ++c) {
        #pragma unroll
        for (int i = 0; i < 8; ++i) {
            int flat4 = i * 256 + tid;
            int r = flat4 >> 4;
            int q = flat4 & 15;
            float4 v = make_float4(0.f, 0.f, 0.f, 0.f);
            if (row0 + r < N)
                v = ((const float4*)x)[(size_t)(row0 + r) * (F_IN / 4) + c * (KC / 4) + q];
            *(float4*)(sx + r * LDP + q * 4) = v;
        }
        #pragma unroll
        for (int i = 0; i < 8; ++i) {
            int flat = i * 256 + tid;
            int k = flat >> 5;
            int f = flat & 31;
            sWt[f * LDP + k] = W[(size_t)(c * KC + k) * F_OUT + f];
        }
        __syncthreads();

        #pragma unroll 4
        for (int k0 = 0; k0 < KC; k0 += 4) {
            float4 wv[4], xv[4];
            #pragma unroll
            for (int m = 0; m < 4; ++m)
                wv[m] = *(const float4*)(sWt + (fbase + 8 * m) * LDP + k0);
            #pragma unroll
            for (int j = 0; j < 4; ++j)
                xv[j] = *(const float4*)(sx + (rbase + 32 * j) * LDP + k0);
            #pragma unroll
            for (int j = 0; j < 4; ++j)
                #pragma unroll
                for (int m = 0; m < 4; ++m)
                    acc[j][m] += xv[j].x * wv[m].x + xv[j].y * wv[m].y +
                                 xv[j].z * wv[m].z + xv[j].w * wv[m].w;
        }
        __syncthreads();
    }

    #pragma unroll
    for (int j = 0; j < 4; ++j) {
        int row = row0 + rbase + 32 * j;
        if (row < N) {
            float di = rsqrtf((float)cnt[row] + 1.0f);
            #pragma unroll
            for (int m = 0; m < 4; ++m)
                hs[(size_t)row * F_OUT + fbase + 8 * m] = acc[j][m] * di;
        }
    }
}

// ---------- CSR fill: adj[atomicAdd(&off[dst],1)] = src ----------
// After this kernel, off[n] == segment END of node n (start = end - cnt[n]).
__global__ __launch_bounds__(256) void k_fill(const int* __restrict__ ei,
                                              int* __restrict__ off,
                                              int* __restrict__ adj,
                                              const int* __restrict__ flag,
                                              int E, int N) {
    int m64 = *flag;
    int t = blockIdx.x * 256 + threadIdx.x;
    int e0 = t * 4;
    if (e0 >= E) return;
    int s4[4], d4[4];
    if (e0 + 3 < E) {
        if (m64) {
            const int4* bs = (const int4*)ei;
            int4 a = bs[2 * t];
            int4 b2 = bs[2 * t + 1];
            s4[0] = a.x; s4[1] = a.z; s4[2] = b2.x; s4[3] = b2.z;
            const int4* bd = (const int4*)(ei + 2 * (size_t)E);
            int4 c = bd[2 * t];
            int4 d2 = bd[2 * t + 1];
            d4[0] = c.x; d4[1] = c.z; d4[2] = d2.x; d4[3] = d2.z;
        } else {
            int4 a = *(const int4*)(ei + e0);
            s4[0] = a.x; s4[1] = a.y; s4[2] = a.z; s4[3] = a.w;
            int4 c = *(const int4*)(ei + (size_t)E + e0);
            d4[0] = c.x; d4[1] = c.y; d4[2] = c.z; d4[3] = c.w;
        }
        #pragma unroll
        for (int j = 0; j < 4; ++j) {
            if ((unsigned)d4[j] < (unsigned)N) {
                int slot = atomicAdd(&off[d4[j]], 1);
                adj[slot] = s4[j];
            }
        }
    } else {
        for (int e = e0; e < E; ++e) {
            int ss = load_idx(ei, e, m64);
            int dd = load_idx(ei, E + e, m64);
            if ((unsigned)dd < (unsigned)N) {
                int slot = atomicAdd(&off[dd], 1);
                adj[slot] = ss;
            }
        }
    }
}

// ---------- gather-aggregate: 16 lanes per node, float2 per lane ----------
// out[n][f] = b[f] + dinv[n] * (hs[n][f] + sum_{src in CSR(n)} hs[src][f])
__global__ __launch_bounds__(256) void k_agg(const float* __restrict__ hs,
                                             const int* __restrict__ adj,
                                             const int* __restrict__ off,
                                             const int* __restrict__ cnt,
                                             const float* __restrict__ b,
                                             float* __restrict__ out, int N) {
    long long gid = (long long)blockIdx.x * 256 + threadIdx.x;
    int n = (int)(gid >> 4);
    int q = (int)(gid & 15);  // feature pair 0..15
    if (n >= N) return;
    int deg = cnt[n];
    int end = off[n];          // post-fill: start + deg
    int start = end - deg;

    float2 hv = ((const float2*)(hs + (size_t)n * F_OUT))[q];
    float ax = hv.x, ay = hv.y;
    float bx = 0.f, by = 0.f;

    int k = start;
    for (; k + 2 <= end; k += 2) {
        int s0 = adj[k];
        int s1 = adj[k + 1];
        if ((unsigned)s0 >= (unsigned)N) s0 = 0;
        if ((unsigned)s1 >= (unsigned)N) s1 = 0;
        float2 v0 = ((const float2*)(hs + (size_t)s0 * F_OUT))[q];
        float2 v1 = ((const float2*)(hs + (size_t)s1 * F_OUT))[q];
        ax += v0.x; ay += v0.y;
        bx += v1.x; by += v1.y;
    }
    if (k < end) {
        int s0 = adj[k];
        if ((unsigned)s0 >= (unsigned)N) s0 = 0;
        float2 v0 = ((const float2*)(hs + (size_t)s0 * F_OUT))[q];
        ax += v0.x; ay += v0.y;
    }

    float di = rsqrtf((float)deg + 1.0f);
    float2 bv = ((const float2*)b)[q];
    float2 o;
    o.x = bv.x + di * (ax + bx);
    o.y = bv.y + di * (ay + by);
    ((float2*)(out + (size_t)n * F_OUT))[q] = o;
}

extern "C" void kernel_launch(void* const* d_in, const int* in_sizes, int n_in,
                              void* d_out, int out_size, void* d_ws, size_t ws_size,
                              hipStream_t stream) {
    const float* x  = (const float*)d_in[0];
    const int*   ei = (const int*)d_in[1];
    const float* W  = (const float*)d_in[2];
    const float* b  = (const float*)d_in[3];
    float* out = (float*)d_out;

    const int N = in_sizes[0] / F_IN;   // 100000
    const int E = in_sizes[1] / 2;      // 1600000

    // ws layout: hs (N*32 f32) | adj (E i32) | off (N i32) | cnt (N i32) | bsum (1024) | flag (1)
    float* hs   = (float*)d_ws;
    int*   adj  = (int*)(hs + (size_t)N * F_OUT);
    int*   off  = adj + (size_t)E;
    int*   cnt  = off + N;
    int*   bsum = cnt + N;
    int*   flag = bsum + 1024;

    const int nb_scan = (N + 1023) / 1024;   // 98 for N=100000 (<=1024 supported)

    k_zero <<<(N + 255) / 256, 256, 0, stream>>>(cnt, ei, flag, N);
    k_count<<<(E / 4 + 255) / 256, 256, 0, stream>>>(ei, cnt, flag, E, N);
    k_scan1<<<nb_scan, 256, 0, stream>>>(cnt, off, bsum, N);
    k_scan2<<<1, 256, 0, stream>>>(bsum, nb_scan);
    k_scan3<<<(N + 255) / 256, 256, 0, stream>>>(off, bsum, N);
    k_gemm <<<(N + 127) / 128, 256, 0, stream>>>(x, W, cnt, hs, N);
    k_fill <<<(E / 4 + 255) / 256, 256, 0, stream>>>(ei, off, adj, flag, E, N);
    long long at = (long long)N * (F_OUT / 2);
    k_agg  <<<(int)((at + 255) / 256), 256, 0, stream>>>(hs, adj, off, cnt, b, out, N);
}